// Round 2
// baseline (16042.941 us; speedup 1.0000x reference)
//
#include <hip/hip_runtime.h>
#include <math.h>

// Backprop_29188597744223 — 1024-step sequential MLP training scan.
//
//   k_gram : G = X·Xᵀ (lower triangle + diag tiles), grid-parallel
//   k_z10  : Z10 = X·W1_init, grid-parallel
//   k2_seq : single workgroup (512 thr) runs all 1024 steps.
//            W1 lazy (Gram trick; scale s1 + ||U1||² tracked in DOUBLE),
//            W2/W3 register-resident, renormalized IN PLACE each step
//            (no lazy scale -> no overflow), biases in LDS.
//   k_w1out: W1_final = s1_f·(W1_init + Xᵀ·diag(c)·O1), grid-parallel

#define LRC  0.01f
#define EPSV 1e-8f

// scl[] indices
#define S1  0
#define N2  1
#define N3  2
#define R2  3
#define R3  4
#define RB1 5
#define RB2 6
#define RB3 7

#define SMEM_FLOATS 31872
#define SMEM_BYTES  (SMEM_FLOATS * 4)

#define FMA16(c, a, b)                                                        \
  c[0][0] += a.x * b.x; c[0][1] += a.x * b.y; c[0][2] += a.x * b.z; c[0][3] += a.x * b.w; \
  c[1][0] += a.y * b.x; c[1][1] += a.y * b.y; c[1][2] += a.y * b.z; c[1][3] += a.y * b.w; \
  c[2][0] += a.z * b.x; c[2][1] += a.z * b.y; c[2][2] += a.z * b.z; c[2][3] += a.z * b.w; \
  c[3][0] += a.w * b.x; c[3][1] += a.w * b.y; c[3][2] += a.w * b.z; c[3][3] += a.w * b.w;

// ---------------------------------------------------------------- k_gram ----
__global__ __launch_bounds__(256) void k_gram(const float* __restrict__ X,
                                              float* __restrict__ G) {
  const int bi = blockIdx.y, bj = blockIdx.x;
  if (bj > bi) return;
  __shared__ float Xa[32][68];
  __shared__ float Xb[32][68];
  const int tid = threadIdx.x;
  const int tx = tid & 15, ty = tid >> 4;
  float c[4][4] = {};
  for (int k0 = 0; k0 < 1024; k0 += 32) {
    __syncthreads();
    {
      const int row = tid >> 2, kk = (tid & 3) * 8;
      const float* pa = X + (bi * 64 + row) * 1024 + k0 + kk;
      const float4 a0 = *(const float4*)pa;
      const float4 a1 = *(const float4*)(pa + 4);
      Xa[kk + 0][row] = a0.x; Xa[kk + 1][row] = a0.y;
      Xa[kk + 2][row] = a0.z; Xa[kk + 3][row] = a0.w;
      Xa[kk + 4][row] = a1.x; Xa[kk + 5][row] = a1.y;
      Xa[kk + 6][row] = a1.z; Xa[kk + 7][row] = a1.w;
      const float* pb = X + (bj * 64 + row) * 1024 + k0 + kk;
      const float4 b0 = *(const float4*)pb;
      const float4 b1 = *(const float4*)(pb + 4);
      Xb[kk + 0][row] = b0.x; Xb[kk + 1][row] = b0.y;
      Xb[kk + 2][row] = b0.z; Xb[kk + 3][row] = b0.w;
      Xb[kk + 4][row] = b1.x; Xb[kk + 5][row] = b1.y;
      Xb[kk + 6][row] = b1.z; Xb[kk + 7][row] = b1.w;
    }
    __syncthreads();
#pragma unroll
    for (int kk = 0; kk < 32; kk++) {
      const float4 a = *(const float4*)&Xa[kk][ty * 4];
      const float4 b = *(const float4*)&Xb[kk][tx * 4];
      FMA16(c, a, b)
    }
  }
#pragma unroll
  for (int ii = 0; ii < 4; ii++) {
    *(float4*)(G + (bi * 64 + ty * 4 + ii) * 1024 + bj * 64 + tx * 4) =
        make_float4(c[ii][0], c[ii][1], c[ii][2], c[ii][3]);
  }
}

// ----------------------------------------------------------------- k_z10 ----
__global__ __launch_bounds__(256) void k_z10(const float* __restrict__ X,
                                             const float* __restrict__ W1g,
                                             float* __restrict__ Z10) {
  const int bi = blockIdx.y, bj = blockIdx.x;
  __shared__ float At[32][68];
  __shared__ float Bt[32][68];
  const int tid = threadIdx.x;
  const int tx = tid & 15, ty = tid >> 4;
  float c[4][4] = {};
  for (int k0 = 0; k0 < 1024; k0 += 32) {
    __syncthreads();
    {
      const int row = tid >> 2, kk = (tid & 3) * 8;
      const float* pa = X + (bi * 64 + row) * 1024 + k0 + kk;
      const float4 a0 = *(const float4*)pa;
      const float4 a1 = *(const float4*)(pa + 4);
      At[kk + 0][row] = a0.x; At[kk + 1][row] = a0.y;
      At[kk + 2][row] = a0.z; At[kk + 3][row] = a0.w;
      At[kk + 4][row] = a1.x; At[kk + 5][row] = a1.y;
      At[kk + 6][row] = a1.z; At[kk + 7][row] = a1.w;
      const int kr = tid >> 3, j8 = (tid & 7) * 8;
      const float* pb = W1g + (k0 + kr) * 256 + bj * 64 + j8;
      *(float4*)&Bt[kr][j8]     = *(const float4*)pb;
      *(float4*)&Bt[kr][j8 + 4] = *(const float4*)(pb + 4);
    }
    __syncthreads();
#pragma unroll
    for (int kk = 0; kk < 32; kk++) {
      const float4 a = *(const float4*)&At[kk][ty * 4];
      const float4 b = *(const float4*)&Bt[kk][tx * 4];
      FMA16(c, a, b)
    }
  }
#pragma unroll
  for (int ii = 0; ii < 4; ii++) {
    *(float4*)(Z10 + (bi * 64 + ty * 4 + ii) * 256 + bj * 64 + tx * 4) =
        make_float4(c[ii][0], c[ii][1], c[ii][2], c[ii][3]);
  }
}

// --------------------------------------------------------------- k_w1out ----
__global__ __launch_bounds__(256) void k_w1out(
    const float* __restrict__ X, const float* __restrict__ o1g,
    const float* __restrict__ cg, const float* __restrict__ W1g,
    const float* __restrict__ sclg, float* __restrict__ outW1) {
  const int bi = blockIdx.y, bj = blockIdx.x;
  __shared__ float At[32][68];
  __shared__ float Bt[32][68];
  const int tid = threadIdx.x;
  const int tx = tid & 15, ty = tid >> 4;
  float c[4][4] = {};
  for (int k0 = 0; k0 < 1024; k0 += 32) {
    __syncthreads();
    {
      const int kr = tid >> 3, m8 = (tid & 7) * 8;
      const float* pa = X + (k0 + kr) * 1024 + bi * 64 + m8;
      *(float4*)&At[kr][m8]     = *(const float4*)pa;
      *(float4*)&At[kr][m8 + 4] = *(const float4*)(pa + 4);
      const float cs = cg[k0 + kr];
      const float* pb = o1g + (k0 + kr) * 256 + bj * 64 + m8;
      float4 b0 = *(const float4*)pb;
      float4 b1 = *(const float4*)(pb + 4);
      b0.x *= cs; b0.y *= cs; b0.z *= cs; b0.w *= cs;
      b1.x *= cs; b1.y *= cs; b1.z *= cs; b1.w *= cs;
      *(float4*)&Bt[kr][m8]     = b0;
      *(float4*)&Bt[kr][m8 + 4] = b1;
    }
    __syncthreads();
#pragma unroll
    for (int kk = 0; kk < 32; kk++) {
      const float4 a = *(const float4*)&At[kk][ty * 4];
      const float4 b = *(const float4*)&Bt[kk][tx * 4];
      FMA16(c, a, b)
    }
  }
  const float s1f = sclg[0];
#pragma unroll
  for (int ii = 0; ii < 4; ii++) {
    const int row = bi * 64 + ty * 4 + ii;
    const float4 w = *(const float4*)(W1g + row * 256 + bj * 64 + tx * 4);
    *(float4*)(outW1 + row * 256 + bj * 64 + tx * 4) =
        make_float4(s1f * (w.x + c[ii][0]), s1f * (w.y + c[ii][1]),
                    s1f * (w.z + c[ii][2]), s1f * (w.w + c[ii][3]));
  }
}

// ---------------------------------------------------------------- k2_seq ----
__device__ __forceinline__ float block_reduce(float v, float* tmp, int tid) {
#pragma unroll
  for (int off = 32; off > 0; off >>= 1) v += __shfl_xor(v, off);
  __syncthreads();
  if ((tid & 63) == 0) tmp[tid >> 6] = v;
  __syncthreads();
  float s = 0.f;
#pragma unroll
  for (int w = 0; w < 8; w++) s += tmp[w];
  return s;
}

__global__ __launch_bounds__(512, 2) void k2_seq(
    const float* __restrict__ Tg, const float* __restrict__ W1g,
    const float* __restrict__ b1g, const float* __restrict__ W2g,
    const float* __restrict__ b2g, const float* __restrict__ W3g,
    const float* __restrict__ b3g, const float* __restrict__ G,
    const float* __restrict__ Z10, float* __restrict__ o1g,
    float* __restrict__ cg, float* __restrict__ z1p, float* __restrict__ sclg,
    float* __restrict__ outW2, float* __restrict__ outW3) {
  extern __shared__ float sm[];
  __shared__ double n1d;           // ||U1||^2 tracked in double (tid0 only)
  float* const o1h = sm;           // [64][256]
  float* const Gb  = sm + 16384;   // [64][64] / [64][33]
  float* const scr = sm + 20480;   // 8448 floats
  float* const a1v = sm + 28928;
  float* const z1v = sm + 29184;
  float* const z2v = sm + 29440;
  float* const a2v = sm + 29696;
  float* const o2v = sm + 29952;
  float* const o1v = sm + 30208;
  float* const b1v = sm + 30464;
  float* const b2v = sm + 30720;
  float* const b1p = sm + 30976;
  float* const b2p = sm + 31232;
  float* const z3v = sm + 31488;
  float* const d3v = sm + 31552;
  float* const b3v = sm + 31616;
  float* const b3p = sm + 31680;
  float* const ch  = sm + 31744;
  float* const dts = sm + 31808;
  float* const scl = sm + 31824;
  float* const cpre = sm + 31840;

  const int tid = threadIdx.x;
  const int p = tid >> 5;  // 0..15
  const int q = tid & 31;  // 0..31

  // Register-resident W2/W3 — ALWAYS the true (normalized) weights.
  float U2[16][8];
  float U3[16][2];
#pragma unroll
  for (int i2 = 0; i2 < 16; i2++) {
    const int row = p * 16 + i2;
    const float4 v0 = *(const float4*)(W2g + row * 256 + q * 8);
    const float4 v1 = *(const float4*)(W2g + row * 256 + q * 8 + 4);
    U2[i2][0] = v0.x; U2[i2][1] = v0.y; U2[i2][2] = v0.z; U2[i2][3] = v0.w;
    U2[i2][4] = v1.x; U2[i2][5] = v1.y; U2[i2][6] = v1.z; U2[i2][7] = v1.w;
    const float2 w3v = *(const float2*)(W3g + row * 64 + q * 2);
    U3[i2][0] = w3v.x; U3[i2][1] = w3v.y;
  }
  if (tid < 256) { b1v[tid] = b1g[tid]; b2v[tid] = b2g[tid]; }
  if (tid < 64) b3v[tid] = b3g[tid];

  float acc1 = 0.f;
  for (int i = tid; i < 65536; i += 512) {
    const float4 v = ((const float4*)W1g)[i];
    acc1 += v.x * v.x + v.y * v.y + v.z * v.z + v.w * v.w;
  }
  const float n1init = block_reduce(acc1, scr, tid);
  float acc2 = 0.f;
#pragma unroll
  for (int i2 = 0; i2 < 16; i2++)
#pragma unroll
    for (int jj = 0; jj < 8; jj++) acc2 += U2[i2][jj] * U2[i2][jj];
  const float n2init = block_reduce(acc2, scr, tid);
  float acc3 = 0.f;
#pragma unroll
  for (int i2 = 0; i2 < 16; i2++)
    acc3 += U3[i2][0] * U3[i2][0] + U3[i2][1] * U3[i2][1];
  const float n3init = block_reduce(acc3, scr, tid);
  if (tid == 0) {
    scl[S1] = 1.f;
    scl[N2] = n2init; scl[N3] = n3init;
    n1d = (double)n1init;
  }
  __syncthreads();

  for (int b = 0; b < 16; b++) {
    const int bs = b * 64;
    // ---- prefix GEMM
    {
      float pacc[4][8];
#pragma unroll
      for (int r2 = 0; r2 < 4; r2++)
#pragma unroll
        for (int jj = 0; jj < 8; jj++) pacc[r2][jj] = 0.f;
      for (int c0 = 0; c0 < bs; c0 += 32) {
        __syncthreads();
        if (tid < 32) cpre[tid] = cg[c0 + tid];
        {
          const int row = tid >> 3, k4 = (tid & 7) * 4;
          const float4 gv = *(const float4*)(G + (bs + row) * 1024 + c0 + k4);
          Gb[row * 33 + k4 + 0] = gv.x; Gb[row * 33 + k4 + 1] = gv.y;
          Gb[row * 33 + k4 + 2] = gv.z; Gb[row * 33 + k4 + 3] = gv.w;
        }
#pragma unroll
        for (int u = 0; u < 4; u++) {
          const int fi = tid + u * 512;
          ((float4*)scr)[fi] = ((const float4*)(o1g + c0 * 256))[fi];
        }
        __syncthreads();
#pragma unroll 2
        for (int ss = 0; ss < 32; ss++) {
          const float cs = cpre[ss];
          const float4 oA = *(const float4*)(scr + ss * 256 + q * 8);
          const float4 oB = *(const float4*)(scr + ss * 256 + q * 8 + 4);
#pragma unroll
          for (int r2 = 0; r2 < 4; r2++) {
            const float g = Gb[(p * 4 + r2) * 33 + ss] * cs;
            pacc[r2][0] += g * oA.x; pacc[r2][1] += g * oA.y;
            pacc[r2][2] += g * oA.z; pacc[r2][3] += g * oA.w;
            pacc[r2][4] += g * oB.x; pacc[r2][5] += g * oB.y;
            pacc[r2][6] += g * oB.z; pacc[r2][7] += g * oB.w;
          }
        }
      }
      __syncthreads();
#pragma unroll
      for (int r2 = 0; r2 < 4; r2++) {
        const int r = p * 4 + r2;
        float4 z0 = *(const float4*)(Z10 + (bs + r) * 256 + q * 8);
        float4 z1 = *(const float4*)(Z10 + (bs + r) * 256 + q * 8 + 4);
        z0.x += pacc[r2][0]; z0.y += pacc[r2][1];
        z0.z += pacc[r2][2]; z0.w += pacc[r2][3];
        z1.x += pacc[r2][4]; z1.y += pacc[r2][5];
        z1.z += pacc[r2][6]; z1.w += pacc[r2][7];
        *(float4*)(z1p + r * 256 + q * 8) = z0;
        *(float4*)(z1p + r * 256 + q * 8 + 4) = z1;
      }
#pragma unroll
      for (int u = 0; u < 2; u++) {
        const int fi = tid + u * 512;
        const int row = fi >> 4, c4 = fi & 15;
        ((float4*)Gb)[fi] = *(const float4*)(G + (bs + row) * 1024 + bs + c4 * 4);
      }
      __syncthreads();
    }

    // ---- 64 sequential steps
    for (int l = 0; l < 64; l++) {
      const int t = bs + l;
      // A
      {
        const int j = tid >> 1, half = tid & 1;
        float a = 0.f;
        for (int lp = half; lp < l; lp += 2)
          a += ch[lp] * Gb[l * 64 + lp] * o1h[lp * 256 + j];
        a += __shfl_xor(a, 1);
        if (half == 0) {
          const float z1u = z1p[l * 256 + j] + a;
          z1v[j] = z1u;
          const float z = scl[S1] * z1u + b1v[j];
          a1v[j] = 1.f / (1.f + expf(-z));
        }
      }
      __syncthreads();
      // B1
      {
        float av[16];
#pragma unroll
        for (int i2 = 0; i2 < 16; i2++) av[i2] = a1v[p * 16 + i2];
        float acc[8];
#pragma unroll
        for (int jj = 0; jj < 8; jj++) acc[jj] = 0.f;
#pragma unroll
        for (int i2 = 0; i2 < 16; i2++)
#pragma unroll
          for (int jj = 0; jj < 8; jj++) acc[jj] += av[i2] * U2[i2][jj];
#pragma unroll
        for (int jj = 0; jj < 8; jj++) {
          const int jr = (jj + q) & 7;
          scr[(q * 8 + jr) * 17 + p] = acc[jr];
        }
      }
      __syncthreads();
      // B2
      if (tid < 256) {
        float s = 0.f;
#pragma unroll
        for (int pp = 0; pp < 16; pp++) s += scr[tid * 17 + pp];
        z2v[tid] = s;
        a2v[tid] = 1.f / (1.f + expf(-(s + b2v[tid])));
      }
      __syncthreads();
      // C1
      {
        float c0a = 0.f, c1a = 0.f;
#pragma unroll
        for (int i2 = 0; i2 < 16; i2++) {
          const float a2x = a2v[p * 16 + i2];
          c0a += a2x * U3[i2][0];
          c1a += a2x * U3[i2][1];
        }
        scr[(q * 2 + 0) * 17 + p] = c0a;
        scr[(q * 2 + 1) * 17 + p] = c1a;
      }
      __syncthreads();
      // C2
      if (tid < 64) {
        float s = 0.f;
#pragma unroll
        for (int pp = 0; pp < 16; pp++) s += scr[tid * 17 + pp];
        z3v[tid] = s;
        const float a3 = 1.f / (1.f + expf(-(s + b3v[tid])));
        const float e = expf(-a3);
        float tot = e;
#pragma unroll
        for (int off = 32; off > 0; off >>= 1) tot += __shfl_xor(tot, off);
        const float outv = e / tot;
        const float d3 = (Tg[t * 64 + tid] - outv) * a3 * (1.f - a3);
        d3v[tid] = d3;
        b3p[tid] = b3v[tid] - LRC * d3;
      }
      __syncthreads();
      // E1
      {
        const float d0 = d3v[q * 2 + 0], d1 = d3v[q * 2 + 1];
#pragma unroll
        for (int i2 = 0; i2 < 16; i2++)
          scr[(p * 16 + i2) * 33 + q] = U3[i2][0] * d0 + U3[i2][1] * d1;
      }
      __syncthreads();
      // E2
      if (tid < 256) {
        float s = 0.f;
#pragma unroll
        for (int qq = 0; qq < 32; qq++) s += scr[tid * 33 + qq];
        const float a2x = a2v[tid];
        const float o2 = s * a2x * (1.f - a2x);
        o2v[tid] = o2;
        b2p[tid] = b2v[tid] - LRC * o2;
      }
      __syncthreads();
      // F1
      {
        float ov[8];
#pragma unroll
        for (int jj = 0; jj < 8; jj++) ov[jj] = o2v[q * 8 + jj];
#pragma unroll
        for (int i2 = 0; i2 < 16; i2++) {
          float s = 0.f;
#pragma unroll
          for (int jj = 0; jj < 8; jj++) s += U2[i2][jj] * ov[jj];
          scr[(p * 16 + i2) * 33 + q] = s;
        }
      }
      __syncthreads();
      // F2
      if (tid < 256) {
        float s = 0.f;
#pragma unroll
        for (int qq = 0; qq < 32; qq++) s += scr[tid * 33 + qq];
        const float a1x = a1v[tid];
        const float o1x = s * a1x * (1.f - a1x);
        o1v[tid] = o1x;
        o1h[l * 256 + tid] = o1x;
        o1g[t * 256 + tid] = o1x;
        b1p[tid] = b1v[tid] - LRC * o1x;
      }
      __syncthreads();
      // G: batched dots
      {
        const int w = tid >> 6, lane = tid & 63;
        float v = 0.f;
        if (w == 0)      { for (int i = lane; i < 256; i += 64) v += z1v[i] * o1v[i]; }
        else if (w == 1) { for (int i = lane; i < 256; i += 64) v += o1v[i] * o1v[i]; }
        else if (w == 2) { for (int i = lane; i < 256; i += 64) v += z2v[i] * o2v[i]; }
        else if (w == 3) { for (int i = lane; i < 256; i += 64) v += a1v[i] * a1v[i]; }
        else if (w == 4) { for (int i = lane; i < 256; i += 64) v += o2v[i] * o2v[i]; }
        else if (w == 5) { v = z3v[lane] * d3v[lane]; }
        else if (w == 6) { for (int i = lane; i < 256; i += 64) v += a2v[i] * a2v[i]; }
        else             { v = d3v[lane] * d3v[lane]; }
#pragma unroll
        for (int off = 32; off > 0; off >>= 1) v += __shfl_xor(v, off);
        if (lane == 0) dts[w] = v;
        float v2 = 0.f;
        if (w == 0)      { for (int i = lane; i < 256; i += 64) v2 += b1p[i] * b1p[i]; }
        else if (w == 1) { for (int i = lane; i < 256; i += 64) v2 += b2p[i] * b2p[i]; }
        else if (w == 2) { v2 = b3p[lane] * b3p[lane]; }
#pragma unroll
        for (int off = 32; off > 0; off >>= 1) v2 += __shfl_xor(v2, off);
        if (lane == 0 && w < 3) dts[8 + w] = v2;
      }
      __syncthreads();
      // scalar recurrences
      if (tid == 0) {
        // W1 (lazy): norm tracked in double to avoid overflow.
        const float s1 = scl[S1];
        const float c1 = -LRC / s1;
        const double gtt = (double)Gb[l * 64 + l];
        const double n1 = n1d + 2.0 * (double)c1 * (double)dts[0] +
                          (double)c1 * (double)c1 * gtt * (double)dts[1];
        n1d = n1;
        const double w1n = (double)s1 * sqrt(n1);
        scl[S1] = (float)((double)s1 / fmax(w1n, (double)EPSV));
        ch[l] = c1;
        cg[t] = c1;
        // W2 (direct): ||W2 - LR*outer||^2 then renorm multiplier.
        const float n2p =
            scl[N2] - 2.f * LRC * dts[2] + LRC * LRC * dts[3] * dts[4];
        const float r2 = 1.f / fmaxf(sqrtf(n2p), EPSV);
        scl[R2] = r2;
        scl[N2] = n2p * r2 * r2;
        // W3 (direct)
        const float n3p =
            scl[N3] - 2.f * LRC * dts[5] + LRC * LRC * dts[6] * dts[7];
        const float r3 = 1.f / fmaxf(sqrtf(n3p), EPSV);
        scl[R3] = r3;
        scl[N3] = n3p * r3 * r3;
        scl[RB1] = 1.f / fmaxf(sqrtf(dts[8]), EPSV);
        scl[RB2] = 1.f / fmaxf(sqrtf(dts[9]), EPSV);
        scl[RB3] = 1.f / fmaxf(sqrtf(dts[10]), EPSV);
      }
      __syncthreads();
      // H: rank-1 update + renormalize W2/W3 in registers; bias renorm
      {
        const float r2 = scl[R2], r3 = scl[R3];
        float ov[8];
#pragma unroll
        for (int jj = 0; jj < 8; jj++) ov[jj] = -LRC * r2 * o2v[q * 8 + jj];
        const float d0 = -LRC * r3 * d3v[q * 2 + 0];
        const float d1 = -LRC * r3 * d3v[q * 2 + 1];
#pragma unroll
        for (int i2 = 0; i2 < 16; i2++) {
          const float a1x = a1v[p * 16 + i2];
#pragma unroll
          for (int jj = 0; jj < 8; jj++)
            U2[i2][jj] = U2[i2][jj] * r2 + a1x * ov[jj];
          const float a2x = a2v[p * 16 + i2];
          U3[i2][0] = U3[i2][0] * r3 + a2x * d0;
          U3[i2][1] = U3[i2][1] * r3 + a2x * d1;
        }
        if (tid < 256) {
          b1v[tid] = b1p[tid] * scl[RB1];
          b2v[tid] = b2p[tid] * scl[RB2];
        }
        if (tid < 64) b3v[tid] = b3p[tid] * scl[RB3];
      }
      __syncthreads();
    }
  }

  if (tid == 0) sclg[0] = scl[S1];
#pragma unroll
  for (int i2 = 0; i2 < 16; i2++) {
    const int row = p * 16 + i2;
    *(float4*)(outW2 + row * 256 + q * 8) =
        make_float4(U2[i2][0], U2[i2][1], U2[i2][2], U2[i2][3]);
    *(float4*)(outW2 + row * 256 + q * 8 + 4) =
        make_float4(U2[i2][4], U2[i2][5], U2[i2][6], U2[i2][7]);
    *(float2*)(outW3 + row * 64 + q * 2) = make_float2(U3[i2][0], U3[i2][1]);
  }
}

// ---------------------------------------------------------------- launch ----
extern "C" void kernel_launch(void* const* d_in, const int* in_sizes, int n_in,
                              void* d_out, int out_size, void* d_ws,
                              size_t ws_size, hipStream_t stream) {
  (void)in_sizes; (void)n_in; (void)out_size; (void)ws_size;
  const float* X   = (const float*)d_in[0];
  const float* Tg  = (const float*)d_in[1];
  const float* W1g = (const float*)d_in[2];
  const float* b1g = (const float*)d_in[3];
  const float* W2g = (const float*)d_in[4];
  const float* b2g = (const float*)d_in[5];
  const float* W3g = (const float*)d_in[6];
  const float* b3g = (const float*)d_in[7];
  float* out = (float*)d_out;
  float* ws  = (float*)d_ws;

  float* G    = ws;
  float* Z10  = G + 1048576;
  float* o1g  = Z10 + 262144;
  float* cg   = o1g + 262144;
  float* z1p  = cg + 1024;
  float* sclg = z1p + 16384;

  (void)hipFuncSetAttribute((const void*)k2_seq,
                            hipFuncAttributeMaxDynamicSharedMemorySize,
                            SMEM_BYTES);

  k_gram<<<dim3(16, 16), 256, 0, stream>>>(X, G);
  k_z10<<<dim3(4, 16), 256, 0, stream>>>(X, W1g, Z10);
  k2_seq<<<dim3(1), dim3(512), SMEM_BYTES, stream>>>(
      Tg, W1g, b1g, W2g, b2g, W3g, b3g, G, Z10, o1g, cg, z1p, sclg,
      out + 262144, out + 327680);
  k_w1out<<<dim3(4, 16), 256, 0, stream>>>(X, o1g, cg, W1g, sclg, out);
}

// Round 3
// 15175.793 us; speedup vs baseline: 1.0571x; 1.0571x over previous
//
#include <hip/hip_runtime.h>
#include <math.h>

// Backprop_29188597744223 — 1024-step sequential MLP training scan.
//
//   k_gram : G = X·Xᵀ (lower triangle + diag tiles), grid-parallel
//   k_z10  : Z10 = X·W1_init, grid-parallel
//   k2_seq : single workgroup (512 thr) runs all 1024 steps.
//            W1 lazy (Gram trick; ||U1||² in double), W2/W3 register-resident
//            (renormalized in place), z1p/o1h share one LDS buffer, targets
//            prefetched to LDS per 64-step block.
//   k_w1out: W1_final = s1_f·(W1_init + Xᵀ·diag(c)·O1), grid-parallel

#define LRC  0.01f
#define EPSV 1e-8f

// scl[] indices
#define S1  0
#define N2  1
#define N3  2
#define R2  3
#define R3  4
#define RB1 5
#define RB2 6
#define RB3 7

#define SMEM_FLOATS 35968
#define SMEM_BYTES  (SMEM_FLOATS * 4)

#define FMA16(c, a, b)                                                        \
  c[0][0] += a.x * b.x; c[0][1] += a.x * b.y; c[0][2] += a.x * b.z; c[0][3] += a.x * b.w; \
  c[1][0] += a.y * b.x; c[1][1] += a.y * b.y; c[1][2] += a.y * b.z; c[1][3] += a.y * b.w; \
  c[2][0] += a.z * b.x; c[2][1] += a.z * b.y; c[2][2] += a.z * b.z; c[2][3] += a.z * b.w; \
  c[3][0] += a.w * b.x; c[3][1] += a.w * b.y; c[3][2] += a.w * b.z; c[3][3] += a.w * b.w;

// ---------------------------------------------------------------- k_gram ----
__global__ __launch_bounds__(256) void k_gram(const float* __restrict__ X,
                                              float* __restrict__ G) {
  const int bi = blockIdx.y, bj = blockIdx.x;
  if (bj > bi) return;
  __shared__ float Xa[32][68];
  __shared__ float Xb[32][68];
  const int tid = threadIdx.x;
  const int tx = tid & 15, ty = tid >> 4;
  float c[4][4] = {};
  for (int k0 = 0; k0 < 1024; k0 += 32) {
    __syncthreads();
    {
      const int row = tid >> 2, kk = (tid & 3) * 8;
      const float* pa = X + (bi * 64 + row) * 1024 + k0 + kk;
      const float4 a0 = *(const float4*)pa;
      const float4 a1 = *(const float4*)(pa + 4);
      Xa[kk + 0][row] = a0.x; Xa[kk + 1][row] = a0.y;
      Xa[kk + 2][row] = a0.z; Xa[kk + 3][row] = a0.w;
      Xa[kk + 4][row] = a1.x; Xa[kk + 5][row] = a1.y;
      Xa[kk + 6][row] = a1.z; Xa[kk + 7][row] = a1.w;
      const float* pb = X + (bj * 64 + row) * 1024 + k0 + kk;
      const float4 b0 = *(const float4*)pb;
      const float4 b1 = *(const float4*)(pb + 4);
      Xb[kk + 0][row] = b0.x; Xb[kk + 1][row] = b0.y;
      Xb[kk + 2][row] = b0.z; Xb[kk + 3][row] = b0.w;
      Xb[kk + 4][row] = b1.x; Xb[kk + 5][row] = b1.y;
      Xb[kk + 6][row] = b1.z; Xb[kk + 7][row] = b1.w;
    }
    __syncthreads();
#pragma unroll
    for (int kk = 0; kk < 32; kk++) {
      const float4 a = *(const float4*)&Xa[kk][ty * 4];
      const float4 b = *(const float4*)&Xb[kk][tx * 4];
      FMA16(c, a, b)
    }
  }
#pragma unroll
  for (int ii = 0; ii < 4; ii++) {
    *(float4*)(G + (bi * 64 + ty * 4 + ii) * 1024 + bj * 64 + tx * 4) =
        make_float4(c[ii][0], c[ii][1], c[ii][2], c[ii][3]);
  }
}

// ----------------------------------------------------------------- k_z10 ----
__global__ __launch_bounds__(256) void k_z10(const float* __restrict__ X,
                                             const float* __restrict__ W1g,
                                             float* __restrict__ Z10) {
  const int bi = blockIdx.y, bj = blockIdx.x;
  __shared__ float At[32][68];
  __shared__ float Bt[32][68];
  const int tid = threadIdx.x;
  const int tx = tid & 15, ty = tid >> 4;
  float c[4][4] = {};
  for (int k0 = 0; k0 < 1024; k0 += 32) {
    __syncthreads();
    {
      const int row = tid >> 2, kk = (tid & 3) * 8;
      const float* pa = X + (bi * 64 + row) * 1024 + k0 + kk;
      const float4 a0 = *(const float4*)pa;
      const float4 a1 = *(const float4*)(pa + 4);
      At[kk + 0][row] = a0.x; At[kk + 1][row] = a0.y;
      At[kk + 2][row] = a0.z; At[kk + 3][row] = a0.w;
      At[kk + 4][row] = a1.x; At[kk + 5][row] = a1.y;
      At[kk + 6][row] = a1.z; At[kk + 7][row] = a1.w;
      const int kr = tid >> 3, j8 = (tid & 7) * 8;
      const float* pb = W1g + (k0 + kr) * 256 + bj * 64 + j8;
      *(float4*)&Bt[kr][j8]     = *(const float4*)pb;
      *(float4*)&Bt[kr][j8 + 4] = *(const float4*)(pb + 4);
    }
    __syncthreads();
#pragma unroll
    for (int kk = 0; kk < 32; kk++) {
      const float4 a = *(const float4*)&At[kk][ty * 4];
      const float4 b = *(const float4*)&Bt[kk][tx * 4];
      FMA16(c, a, b)
    }
  }
#pragma unroll
  for (int ii = 0; ii < 4; ii++) {
    *(float4*)(Z10 + (bi * 64 + ty * 4 + ii) * 256 + bj * 64 + tx * 4) =
        make_float4(c[ii][0], c[ii][1], c[ii][2], c[ii][3]);
  }
}

// --------------------------------------------------------------- k_w1out ----
__global__ __launch_bounds__(256) void k_w1out(
    const float* __restrict__ X, const float* __restrict__ o1g,
    const float* __restrict__ cg, const float* __restrict__ W1g,
    const float* __restrict__ sclg, float* __restrict__ outW1) {
  const int bi = blockIdx.y, bj = blockIdx.x;
  __shared__ float At[32][68];
  __shared__ float Bt[32][68];
  const int tid = threadIdx.x;
  const int tx = tid & 15, ty = tid >> 4;
  float c[4][4] = {};
  for (int k0 = 0; k0 < 1024; k0 += 32) {
    __syncthreads();
    {
      const int kr = tid >> 3, m8 = (tid & 7) * 8;
      const float* pa = X + (k0 + kr) * 1024 + bi * 64 + m8;
      *(float4*)&At[kr][m8]     = *(const float4*)pa;
      *(float4*)&At[kr][m8 + 4] = *(const float4*)(pa + 4);
      const float cs = cg[k0 + kr];
      const float* pb = o1g + (k0 + kr) * 256 + bj * 64 + m8;
      float4 b0 = *(const float4*)pb;
      float4 b1 = *(const float4*)(pb + 4);
      b0.x *= cs; b0.y *= cs; b0.z *= cs; b0.w *= cs;
      b1.x *= cs; b1.y *= cs; b1.z *= cs; b1.w *= cs;
      *(float4*)&Bt[kr][m8]     = b0;
      *(float4*)&Bt[kr][m8 + 4] = b1;
    }
    __syncthreads();
#pragma unroll
    for (int kk = 0; kk < 32; kk++) {
      const float4 a = *(const float4*)&At[kk][ty * 4];
      const float4 b = *(const float4*)&Bt[kk][tx * 4];
      FMA16(c, a, b)
    }
  }
  const float s1f = sclg[0];
#pragma unroll
  for (int ii = 0; ii < 4; ii++) {
    const int row = bi * 64 + ty * 4 + ii;
    const float4 w = *(const float4*)(W1g + row * 256 + bj * 64 + tx * 4);
    *(float4*)(outW1 + row * 256 + bj * 64 + tx * 4) =
        make_float4(s1f * (w.x + c[ii][0]), s1f * (w.y + c[ii][1]),
                    s1f * (w.z + c[ii][2]), s1f * (w.w + c[ii][3]));
  }
}

// ---------------------------------------------------------------- k2_seq ----
__device__ __forceinline__ float block_reduce(float v, float* tmp, int tid) {
#pragma unroll
  for (int off = 32; off > 0; off >>= 1) v += __shfl_xor(v, off);
  __syncthreads();
  if ((tid & 63) == 0) tmp[tid >> 6] = v;
  __syncthreads();
  float s = 0.f;
#pragma unroll
  for (int w = 0; w < 8; w++) s += tmp[w];
  return s;
}

__global__ __attribute__((amdgpu_flat_work_group_size(512, 512)))
__attribute__((amdgpu_waves_per_eu(2, 2))) void k2_seq(
    const float* __restrict__ Tg, const float* __restrict__ W1g,
    const float* __restrict__ b1g, const float* __restrict__ W2g,
    const float* __restrict__ b2g, const float* __restrict__ W3g,
    const float* __restrict__ b3g, const float* __restrict__ G,
    const float* __restrict__ Z10, float* __restrict__ o1g,
    float* __restrict__ cg, float* __restrict__ sclg,
    float* __restrict__ outW2, float* __restrict__ outW3) {
  extern __shared__ float sm[];
  __shared__ double n1d;           // ||U1||^2 tracked in double (tid0 only)
  float* const zo  = sm;           // [64][256]: z1p row l until step l, then o1
  float* const Gb  = sm + 16384;   // [64][64] / [64][33]
  float* const scr = sm + 20480;   // 8448 floats
  float* const Tb  = sm + 28928;   // [64][64] targets for this block
  float* const a1v = sm + 33024;
  float* const z1v = sm + 33280;
  float* const z2v = sm + 33536;
  float* const a2v = sm + 33792;
  float* const o2v = sm + 34048;
  float* const o1v = sm + 34304;
  float* const b1v = sm + 34560;
  float* const b2v = sm + 34816;
  float* const b1p = sm + 35072;
  float* const b2p = sm + 35328;
  float* const z3v = sm + 35584;   // 64
  float* const d3v = sm + 35648;   // 64
  float* const b3v = sm + 35712;   // 64
  float* const b3p = sm + 35776;   // 64
  float* const ch  = sm + 35840;   // 64
  float* const dts = sm + 35904;   // 16
  float* const scl = sm + 35920;   // 16
  float* const cpre = sm + 35936;  // 32

  const int tid = threadIdx.x;
  const int p = tid >> 5;  // 0..15
  const int q = tid & 31;  // 0..31

  // Register-resident W2/W3 — ALWAYS the true (normalized) weights.
  float U2[16][8];
  float U3[16][2];
#pragma unroll
  for (int i2 = 0; i2 < 16; i2++) {
    const int row = p * 16 + i2;
    const float4 v0 = *(const float4*)(W2g + row * 256 + q * 8);
    const float4 v1 = *(const float4*)(W2g + row * 256 + q * 8 + 4);
    U2[i2][0] = v0.x; U2[i2][1] = v0.y; U2[i2][2] = v0.z; U2[i2][3] = v0.w;
    U2[i2][4] = v1.x; U2[i2][5] = v1.y; U2[i2][6] = v1.z; U2[i2][7] = v1.w;
    const float2 w3v = *(const float2*)(W3g + row * 64 + q * 2);
    U3[i2][0] = w3v.x; U3[i2][1] = w3v.y;
  }
  if (tid < 256) { b1v[tid] = b1g[tid]; b2v[tid] = b2g[tid]; }
  if (tid < 64) b3v[tid] = b3g[tid];

  float acc1 = 0.f;
  for (int i = tid; i < 65536; i += 512) {
    const float4 v = ((const float4*)W1g)[i];
    acc1 += v.x * v.x + v.y * v.y + v.z * v.z + v.w * v.w;
  }
  const float n1init = block_reduce(acc1, scr, tid);
  float acc2 = 0.f;
#pragma unroll
  for (int i2 = 0; i2 < 16; i2++)
#pragma unroll
    for (int jj = 0; jj < 8; jj++) acc2 += U2[i2][jj] * U2[i2][jj];
  const float n2init = block_reduce(acc2, scr, tid);
  float acc3 = 0.f;
#pragma unroll
  for (int i2 = 0; i2 < 16; i2++)
    acc3 += U3[i2][0] * U3[i2][0] + U3[i2][1] * U3[i2][1];
  const float n3init = block_reduce(acc3, scr, tid);
  if (tid == 0) {
    scl[S1] = 1.f;
    scl[N2] = n2init; scl[N3] = n3init;
    n1d = (double)n1init;
  }
  __syncthreads();

  for (int b = 0; b < 16; b++) {
    const int bs = b * 64;
    // ---- prefix: zo[r][j] = Z10[bs+r][j] + sum_{s<bs} cg[s] G[bs+r][s] o1[s][j]
    {
      float pacc[4][8];
#pragma unroll
      for (int r2 = 0; r2 < 4; r2++)
#pragma unroll
        for (int jj = 0; jj < 8; jj++) pacc[r2][jj] = 0.f;
      for (int c0 = 0; c0 < bs; c0 += 32) {
        __syncthreads();
        if (tid < 32) cpre[tid] = cg[c0 + tid];
        {
          const int row = tid >> 3, k4 = (tid & 7) * 4;
          const float4 gv = *(const float4*)(G + (bs + row) * 1024 + c0 + k4);
          Gb[row * 33 + k4 + 0] = gv.x; Gb[row * 33 + k4 + 1] = gv.y;
          Gb[row * 33 + k4 + 2] = gv.z; Gb[row * 33 + k4 + 3] = gv.w;
        }
#pragma unroll
        for (int u = 0; u < 4; u++) {
          const int fi = tid + u * 512;
          ((float4*)scr)[fi] = ((const float4*)(o1g + c0 * 256))[fi];
        }
        __syncthreads();
#pragma unroll 2
        for (int ss = 0; ss < 32; ss++) {
          const float cs = cpre[ss];
          const float4 oA = *(const float4*)(scr + ss * 256 + q * 8);
          const float4 oB = *(const float4*)(scr + ss * 256 + q * 8 + 4);
#pragma unroll
          for (int r2 = 0; r2 < 4; r2++) {
            const float g = Gb[(p * 4 + r2) * 33 + ss] * cs;
            pacc[r2][0] += g * oA.x; pacc[r2][1] += g * oA.y;
            pacc[r2][2] += g * oA.z; pacc[r2][3] += g * oA.w;
            pacc[r2][4] += g * oB.x; pacc[r2][5] += g * oB.y;
            pacc[r2][6] += g * oB.z; pacc[r2][7] += g * oB.w;
          }
        }
      }
      __syncthreads();
#pragma unroll
      for (int r2 = 0; r2 < 4; r2++) {
        const int r = p * 4 + r2;
        float4 z0 = *(const float4*)(Z10 + (bs + r) * 256 + q * 8);
        float4 z1 = *(const float4*)(Z10 + (bs + r) * 256 + q * 8 + 4);
        z0.x += pacc[r2][0]; z0.y += pacc[r2][1];
        z0.z += pacc[r2][2]; z0.w += pacc[r2][3];
        z1.x += pacc[r2][4]; z1.y += pacc[r2][5];
        z1.z += pacc[r2][6]; z1.w += pacc[r2][7];
        *(float4*)(zo + r * 256 + q * 8) = z0;
        *(float4*)(zo + r * 256 + q * 8 + 4) = z1;
      }
      // this block's 64x64 Gram square (plain layout) + targets
#pragma unroll
      for (int u = 0; u < 2; u++) {
        const int fi = tid + u * 512;
        const int row = fi >> 4, c4 = fi & 15;
        ((float4*)Gb)[fi] = *(const float4*)(G + (bs + row) * 1024 + bs + c4 * 4);
      }
      ((float4*)Tb)[tid]       = ((const float4*)(Tg + bs * 64))[tid];
      ((float4*)Tb)[tid + 512] = ((const float4*)(Tg + bs * 64))[tid + 512];
      __syncthreads();
    }

    // ---- 64 sequential steps
    for (int l = 0; l < 64; l++) {
      const int t = bs + l;
      // A: z1u = zo[l] (z1p) + in-block history; a1 = sigmoid(s1*z1u + b1)
      {
        const int j = tid >> 1, half = tid & 1;
        float a = 0.f;
        for (int lp = half; lp < l; lp += 2)
          a += ch[lp] * Gb[l * 64 + lp] * zo[lp * 256 + j];
        a += __shfl_xor(a, 1);
        if (half == 0) {
          const float z1u = zo[l * 256 + j] + a;
          z1v[j] = z1u;
          const float z = scl[S1] * z1u + b1v[j];
          a1v[j] = 1.f / (1.f + expf(-z));
        }
      }
      __syncthreads();
      // B1: z2 partials = a1 @ U2  (static indices; float4 stores, row/p layout)
      {
        float av[16];
#pragma unroll
        for (int i2 = 0; i2 < 16; i2++) av[i2] = a1v[p * 16 + i2];
        float acc[8];
#pragma unroll
        for (int jj = 0; jj < 8; jj++) acc[jj] = 0.f;
#pragma unroll
        for (int i2 = 0; i2 < 16; i2++)
#pragma unroll
          for (int jj = 0; jj < 8; jj++) acc[jj] += av[i2] * U2[i2][jj];
        *(float4*)&scr[p * 264 + q * 8] =
            make_float4(acc[0], acc[1], acc[2], acc[3]);
        *(float4*)&scr[p * 264 + q * 8 + 4] =
            make_float4(acc[4], acc[5], acc[6], acc[7]);
      }
      __syncthreads();
      // B2
      if (tid < 256) {
        float s = 0.f;
#pragma unroll
        for (int pp = 0; pp < 16; pp++) s += scr[pp * 264 + tid];
        z2v[tid] = s;
        a2v[tid] = 1.f / (1.f + expf(-(s + b2v[tid])));
      }
      __syncthreads();
      // C1: z3 partials = a2 @ U3
      {
        float c0a = 0.f, c1a = 0.f;
#pragma unroll
        for (int i2 = 0; i2 < 16; i2++) {
          const float a2x = a2v[p * 16 + i2];
          c0a += a2x * U3[i2][0];
          c1a += a2x * U3[i2][1];
        }
        scr[(q * 2 + 0) * 17 + p] = c0a;
        scr[(q * 2 + 1) * 17 + p] = c1a;
      }
      __syncthreads();
      // C2: z3, a3, softmax(-a3), d3, b3'
      if (tid < 64) {
        float s = 0.f;
#pragma unroll
        for (int pp = 0; pp < 16; pp++) s += scr[tid * 17 + pp];
        z3v[tid] = s;
        const float a3 = 1.f / (1.f + expf(-(s + b3v[tid])));
        const float e = expf(-a3);
        float tot = e;
#pragma unroll
        for (int off = 32; off > 0; off >>= 1) tot += __shfl_xor(tot, off);
        const float outv = e / tot;
        const float d3 = (Tb[l * 64 + tid] - outv) * a3 * (1.f - a3);
        d3v[tid] = d3;
        b3p[tid] = b3v[tid] - LRC * d3;
      }
      __syncthreads();
      // E1: o2 partials = U3 @ d3
      {
        const float d0 = d3v[q * 2 + 0], d1 = d3v[q * 2 + 1];
#pragma unroll
        for (int i2 = 0; i2 < 16; i2++)
          scr[(p * 16 + i2) * 33 + q] = U3[i2][0] * d0 + U3[i2][1] * d1;
      }
      __syncthreads();
      // E2
      if (tid < 256) {
        float s = 0.f;
#pragma unroll
        for (int qq = 0; qq < 32; qq++) s += scr[tid * 33 + qq];
        const float a2x = a2v[tid];
        const float o2 = s * a2x * (1.f - a2x);
        o2v[tid] = o2;
        b2p[tid] = b2v[tid] - LRC * o2;
      }
      __syncthreads();
      // F1: o1 partials = U2 @ o2
      {
        float ov[8];
#pragma unroll
        for (int jj = 0; jj < 8; jj++) ov[jj] = o2v[q * 8 + jj];
#pragma unroll
        for (int i2 = 0; i2 < 16; i2++) {
          float s = 0.f;
#pragma unroll
          for (int jj = 0; jj < 8; jj++) s += U2[i2][jj] * ov[jj];
          scr[(p * 16 + i2) * 33 + q] = s;
        }
      }
      __syncthreads();
      // F2
      if (tid < 256) {
        float s = 0.f;
#pragma unroll
        for (int qq = 0; qq < 32; qq++) s += scr[tid * 33 + qq];
        const float a1x = a1v[tid];
        const float o1x = s * a1x * (1.f - a1x);
        o1v[tid] = o1x;
        zo[l * 256 + tid] = o1x;          // overwrite z1p row l with o1
        o1g[t * 256 + tid] = o1x;
        b1p[tid] = b1v[tid] - LRC * o1x;
      }
      __syncthreads();
      // G: batched dots
      {
        const int w = tid >> 6, lane = tid & 63;
        float v = 0.f;
        if (w == 0)      { for (int i = lane; i < 256; i += 64) v += z1v[i] * o1v[i]; }
        else if (w == 1) { for (int i = lane; i < 256; i += 64) v += o1v[i] * o1v[i]; }
        else if (w == 2) { for (int i = lane; i < 256; i += 64) v += z2v[i] * o2v[i]; }
        else if (w == 3) { for (int i = lane; i < 256; i += 64) v += a1v[i] * a1v[i]; }
        else if (w == 4) { for (int i = lane; i < 256; i += 64) v += o2v[i] * o2v[i]; }
        else if (w == 5) { v = z3v[lane] * d3v[lane]; }
        else if (w == 6) { for (int i = lane; i < 256; i += 64) v += a2v[i] * a2v[i]; }
        else             { v = d3v[lane] * d3v[lane]; }
#pragma unroll
        for (int off = 32; off > 0; off >>= 1) v += __shfl_xor(v, off);
        if (lane == 0) dts[w] = v;
        float v2 = 0.f;
        if (w == 0)      { for (int i = lane; i < 256; i += 64) v2 += b1p[i] * b1p[i]; }
        else if (w == 1) { for (int i = lane; i < 256; i += 64) v2 += b2p[i] * b2p[i]; }
        else if (w == 2) { v2 = b3p[lane] * b3p[lane]; }
#pragma unroll
        for (int off = 32; off > 0; off >>= 1) v2 += __shfl_xor(v2, off);
        if (lane == 0 && w < 3) dts[8 + w] = v2;
      }
      __syncthreads();
      // scalar recurrences
      if (tid == 0) {
        const float s1 = scl[S1];
        const float c1 = -LRC / s1;
        const double gtt = (double)Gb[l * 64 + l];
        const double n1 = n1d + 2.0 * (double)c1 * (double)dts[0] +
                          (double)c1 * (double)c1 * gtt * (double)dts[1];
        n1d = n1;
        const double w1n = (double)s1 * sqrt(n1);
        scl[S1] = (float)((double)s1 / fmax(w1n, (double)EPSV));
        ch[l] = c1;
        cg[t] = c1;
        const float n2p =
            scl[N2] - 2.f * LRC * dts[2] + LRC * LRC * dts[3] * dts[4];
        const float r2 = 1.f / fmaxf(sqrtf(n2p), EPSV);
        scl[R2] = r2;
        scl[N2] = n2p * r2 * r2;
        const float n3p =
            scl[N3] - 2.f * LRC * dts[5] + LRC * LRC * dts[6] * dts[7];
        const float r3 = 1.f / fmaxf(sqrtf(n3p), EPSV);
        scl[R3] = r3;
        scl[N3] = n3p * r3 * r3;
        scl[RB1] = 1.f / fmaxf(sqrtf(dts[8]), EPSV);
        scl[RB2] = 1.f / fmaxf(sqrtf(dts[9]), EPSV);
        scl[RB3] = 1.f / fmaxf(sqrtf(dts[10]), EPSV);
      }
      __syncthreads();
      // H: rank-1 update + renormalize W2/W3 in registers; bias renorm
      {
        const float r2 = scl[R2], r3 = scl[R3];
        float ov[8];
#pragma unroll
        for (int jj = 0; jj < 8; jj++) ov[jj] = -LRC * r2 * o2v[q * 8 + jj];
        const float d0 = -LRC * r3 * d3v[q * 2 + 0];
        const float d1 = -LRC * r3 * d3v[q * 2 + 1];
#pragma unroll
        for (int i2 = 0; i2 < 16; i2++) {
          const float a1x = a1v[p * 16 + i2];
#pragma unroll
          for (int jj = 0; jj < 8; jj++)
            U2[i2][jj] = U2[i2][jj] * r2 + a1x * ov[jj];
          const float a2x = a2v[p * 16 + i2];
          U3[i2][0] = U3[i2][0] * r3 + a2x * d0;
          U3[i2][1] = U3[i2][1] * r3 + a2x * d1;
        }
        if (tid < 256) {
          b1v[tid] = b1p[tid] * scl[RB1];
          b2v[tid] = b2p[tid] * scl[RB2];
        }
        if (tid < 64) b3v[tid] = b3p[tid] * scl[RB3];
      }
      __syncthreads();
    }
  }

  if (tid == 0) sclg[0] = scl[S1];
#pragma unroll
  for (int i2 = 0; i2 < 16; i2++) {
    const int row = p * 16 + i2;
    *(float4*)(outW2 + row * 256 + q * 8) =
        make_float4(U2[i2][0], U2[i2][1], U2[i2][2], U2[i2][3]);
    *(float4*)(outW2 + row * 256 + q * 8 + 4) =
        make_float4(U2[i2][4], U2[i2][5], U2[i2][6], U2[i2][7]);
    *(float2*)(outW3 + row * 64 + q * 2) = make_float2(U3[i2][0], U3[i2][1]);
  }
}

// ---------------------------------------------------------------- launch ----
extern "C" void kernel_launch(void* const* d_in, const int* in_sizes, int n_in,
                              void* d_out, int out_size, void* d_ws,
                              size_t ws_size, hipStream_t stream) {
  (void)in_sizes; (void)n_in; (void)out_size; (void)ws_size;
  const float* X   = (const float*)d_in[0];
  const float* Tg  = (const float*)d_in[1];
  const float* W1g = (const float*)d_in[2];
  const float* b1g = (const float*)d_in[3];
  const float* W2g = (const float*)d_in[4];
  const float* b2g = (const float*)d_in[5];
  const float* W3g = (const float*)d_in[6];
  const float* b3g = (const float*)d_in[7];
  float* out = (float*)d_out;
  float* ws  = (float*)d_ws;

  float* G    = ws;
  float* Z10  = G + 1048576;
  float* o1g  = Z10 + 262144;
  float* cg   = o1g + 262144;
  float* sclg = cg + 1024;

  (void)hipFuncSetAttribute((const void*)k2_seq,
                            hipFuncAttributeMaxDynamicSharedMemorySize,
                            SMEM_BYTES);

  k_gram<<<dim3(16, 16), 256, 0, stream>>>(X, G);
  k_z10<<<dim3(4, 16), 256, 0, stream>>>(X, W1g, Z10);
  k2_seq<<<dim3(1), dim3(512), SMEM_BYTES, stream>>>(
      Tg, W1g, b1g, W2g, b2g, W3g, b3g, G, Z10, o1g, cg, sclg,
      out + 262144, out + 327680);
  k_w1out<<<dim3(4, 16), 256, 0, stream>>>(X, o1g, cg, W1g, sclg, out);
}